// Round 4
// baseline (107.843 us; speedup 1.0000x reference)
//
#include <hip/hip_runtime.h>
#include <math.h>

#define B_    16
#define N_    128
#define F_IN_ 8
#define S_    8
#define F_OUT_ 64
#define KN_HID_ 32
#define FC_HID_ 32

// workspace layout (float offsets)
//  nodes: [B*N][F_OUT] = 131072  (post-relu node features, pooled by k3)
#define NODE_OFF  0

// ---------------------------------------------------------------------------
// k2: fused ECCConv via the T-factorization.
//   T[k,f]  = sum_{i active} h[b,n,i,k] * X[b,i,f]   (32x8 per node)
//   T[32,f] = sum_{i active} X[b,i,f]                (bias row)
//   node[o] = relu( sum_{kf} T[kf]*w2ext[kf,o] + X[b,n]@root_w + conv_b )
// E rows are read on demand per ACTIVE edge only (32 B broadcast + prefetch).
// Contraction: lane=(g,q) owns o in [4q,4q+4), kf strided by g; float4 loads
// of kn_w2 then 2-round shfl_xor reduction over g.
// Grid: 256 blocks x 256 thr; block = 8 nodes (same batch), wave = 2 nodes.
// ---------------------------------------------------------------------------
__global__ __launch_bounds__(256) void k2_fused(
    const float* __restrict__ A, const float* __restrict__ X,
    const float* __restrict__ E,
    const float* __restrict__ kn_w1, const float* __restrict__ kn_b1,
    const float* __restrict__ kn_w2, const float* __restrict__ kn_b2,
    const float* __restrict__ root_w, const float* __restrict__ conv_b,
    float* __restrict__ ws)
{
    __shared__ float Xlds[N_ * F_IN_];          // 4 KB, whole X row of batch b
    __shared__ float Tlds[4][2][264];           // 8.4 KB

    const int t    = threadIdx.x;
    const int lane = t & 63;
    const int wave = t >> 6;
    const int h2   = lane >> 5;                 // f-group: 0 -> f 0..3, 1 -> 4..7
    const int j    = lane & 31;                 // h index this lane owns
    const int b    = blockIdx.x >> 4;           // 16 blocks per batch
    const int bn0  = blockIdx.x * 8 + wave * 2; // first of this wave's 2 nodes

    // stage X[b,:,:] (4 KB) once per block
    ((float4*)Xlds)[t] = ((const float4*)(X + b * N_ * F_IN_))[t];

    // per-lane column j of kn_w1
    float w1j[S_];
#pragma unroll
    for (int s = 0; s < S_; ++s) w1j[s] = kn_w1[s * KN_HID_ + j];
    const float b1j = kn_b1[j];

    // adjacency rows for both nodes
    float a0[2], a1[2];
#pragma unroll
    for (int nn = 0; nn < 2; ++nn) {
        const int bn = bn0 + nn;
        a0[nn] = A[(size_t)bn * N_ + lane];
        a1[nn] = A[(size_t)bn * N_ + 64 + lane];
    }
    __syncthreads();   // Xlds cross-wave visibility

    const float4* __restrict__ Xl4 = (const float4*)Xlds;

    // ---- edge phase: accumulate T (A values are exactly 1.0) ---------------
#pragma unroll
    for (int nn = 0; nn < 2; ++nn) {
        const int bn = bn0 + nn;
        const unsigned long long mA = __ballot(a0[nn] != 0.f);
        const unsigned long long mB = __ballot(a1[nn] != 0.f);
        const float* __restrict__ Eb = E + (size_t)bn * N_ * S_ + (lane & 7);

        float T[4]  = {0.f, 0.f, 0.f, 0.f};
        float xs[4] = {0.f, 0.f, 0.f, 0.f};

#pragma unroll
        for (int half = 0; half < 2; ++half) {
            unsigned long long m = half ? mB : mA;
            if (!m) continue;
            int i = __builtin_ctzll(m) + half * 64;
            m &= m - 1;
            float ev = Eb[i * S_];              // 32 B broadcast load
            while (true) {
                // prefetch next edge's E values before the compute chain
                int inext = -1; float evnext = 0.f;
                if (m) {
                    inext = __builtin_ctzll(m) + half * 64;
                    m &= m - 1;
                    evnext = Eb[inext * S_];
                }
                float hv = b1j;
#pragma unroll
                for (int s = 0; s < S_; ++s)
                    hv += __shfl(ev, s) * w1j[s];
                hv = hv > 0.f ? hv : 0.f;       // h[j]

                const float4 xf = Xl4[i * 2 + h2];
                T[0] += hv * xf.x;  T[1] += hv * xf.y;
                T[2] += hv * xf.z;  T[3] += hv * xf.w;
                xs[0] += xf.x; xs[1] += xf.y; xs[2] += xf.z; xs[3] += xf.w;

                if (inext < 0) break;
                i = inext; ev = evnext;
            }
        }

        float4* __restrict__ Tl4 = (float4*)Tlds[wave][nn];
        Tl4[j * 2 + h2] = make_float4(T[0], T[1], T[2], T[3]);
        if (j == 0)
            Tl4[64 + h2] = make_float4(xs[0], xs[1], xs[2], xs[3]);
    }
    // same-wave LDS write->read: compiler inserts lgkmcnt waits, no barrier

    // ---- contraction: lane=(g,q); o in [4q,4q+4), kf = g,g+4,... -----------
    const int q = lane & 15;
    const int g = lane >> 4;
    const float* __restrict__ T0 = Tlds[wave][0];
    const float* __restrict__ T1 = Tlds[wave][1];
    const float4* __restrict__ W4 = (const float4*)kn_w2;
    const float4* __restrict__ B4 = (const float4*)kn_b2;

    float4 acc0 = make_float4(0.f, 0.f, 0.f, 0.f);
    float4 acc1 = make_float4(0.f, 0.f, 0.f, 0.f);
#pragma unroll 8
    for (int kf = g; kf < 256; kf += 4) {
        const float4 w = W4[kf * 16 + q];       // coalesced 16B, L1-hot
        const float t0 = T0[kf], t1 = T1[kf];   // 4 distinct addrs, no conflict
        acc0.x += t0 * w.x; acc0.y += t0 * w.y; acc0.z += t0 * w.z; acc0.w += t0 * w.w;
        acc1.x += t1 * w.x; acc1.y += t1 * w.y; acc1.z += t1 * w.z; acc1.w += t1 * w.w;
    }
#pragma unroll
    for (int f = g; f < F_IN_; f += 4) {
        const float4 w = B4[f * 16 + q];
        const float t0 = T0[256 + f], t1 = T1[256 + f];
        acc0.x += t0 * w.x; acc0.y += t0 * w.y; acc0.z += t0 * w.z; acc0.w += t0 * w.w;
        acc1.x += t1 * w.x; acc1.y += t1 * w.y; acc1.z += t1 * w.z; acc1.w += t1 * w.w;
    }

    // butterfly-reduce over g (lanes q, q+16, q+32, q+48)
#pragma unroll
    for (int d = 16; d < 64; d <<= 1) {
        acc0.x += __shfl_xor(acc0.x, d); acc0.y += __shfl_xor(acc0.y, d);
        acc0.z += __shfl_xor(acc0.z, d); acc0.w += __shfl_xor(acc0.w, d);
        acc1.x += __shfl_xor(acc1.x, d); acc1.y += __shfl_xor(acc1.y, d);
        acc1.z += __shfl_xor(acc1.z, d); acc1.w += __shfl_xor(acc1.w, d);
    }

    // ---- epilogue: + X[b,n]@root_w + conv_b, relu, store (g==0 lanes) ------
    const float4* __restrict__ R4 = (const float4*)root_w;
    const float4 cb = ((const float4*)conv_b)[q];
#pragma unroll
    for (int nn = 0; nn < 2; ++nn) {
        const int bn = bn0 + nn;
        const int n  = bn & (N_ - 1);
        float4 r = (nn == 0) ? acc0 : acc1;
        r.x += cb.x; r.y += cb.y; r.z += cb.z; r.w += cb.w;
#pragma unroll
        for (int f = 0; f < F_IN_; ++f) {
            const float xv = Xlds[n * F_IN_ + f];
            const float4 rw = R4[f * 16 + q];
            r.x += xv * rw.x; r.y += xv * rw.y; r.z += xv * rw.z; r.w += xv * rw.w;
        }
        r.x = r.x > 0.f ? r.x : 0.f;  r.y = r.y > 0.f ? r.y : 0.f;
        r.z = r.z > 0.f ? r.z : 0.f;  r.w = r.w > 0.f ? r.w : 0.f;
        if (g == 0)
            ((float4*)(ws + NODE_OFF + (size_t)bn * F_OUT_))[q] = r;
    }
}

// ---------------------------------------------------------------------------
// k3: pooling + head. One 256-thread block per batch element.
// ---------------------------------------------------------------------------
__global__ __launch_bounds__(256) void k3_head(
    const float* __restrict__ fc_w, const float* __restrict__ fc_b,
    const float* __restrict__ out_w, const float* __restrict__ out_b,
    const float* __restrict__ ws, float* __restrict__ out)
{
    const int b = blockIdx.x;
    const int t = threadIdx.x;
    const int o = t & 63;
    const int g = t >> 6;

    float p = 0.f;
    for (int n = g; n < N_; n += 4)
        p += ws[NODE_OFF + (size_t)(b * N_ + n) * F_OUT_ + o];

    __shared__ float red[4][F_OUT_];
    __shared__ float pm[F_OUT_];
    __shared__ float y[FC_HID_];
    red[g][o] = p;
    __syncthreads();

    if (t < F_OUT_)
        pm[t] = (red[0][t] + red[1][t] + red[2][t] + red[3][t]) * (1.0f / (float)N_);
    __syncthreads();

    if (t < FC_HID_) {
        float v = fc_b[t];
#pragma unroll
        for (int o2 = 0; o2 < F_OUT_; ++o2) v += pm[o2] * fc_w[o2 * FC_HID_ + t];
        y[t] = v > 0.f ? v : 0.f;
    }
    __syncthreads();

    if (t == 0) {
        float z = out_b[0];
#pragma unroll
        for (int qq = 0; qq < FC_HID_; ++qq) z += y[qq] * out_w[qq];
        out[b] = 1.f / (1.f + expf(-z));
    }
}

extern "C" void kernel_launch(void* const* d_in, const int* in_sizes, int n_in,
                              void* d_out, int out_size, void* d_ws, size_t ws_size,
                              hipStream_t stream)
{
    const float* A      = (const float*)d_in[0];
    const float* X      = (const float*)d_in[1];
    const float* E      = (const float*)d_in[2];
    const float* kn_w1  = (const float*)d_in[3];
    const float* kn_b1  = (const float*)d_in[4];
    const float* kn_w2  = (const float*)d_in[5];
    const float* kn_b2  = (const float*)d_in[6];
    const float* root_w = (const float*)d_in[7];
    const float* conv_b = (const float*)d_in[8];
    const float* fc_w   = (const float*)d_in[9];
    const float* fc_b   = (const float*)d_in[10];
    const float* out_w  = (const float*)d_in[11];
    const float* out_b  = (const float*)d_in[12];

    float* ws  = (float*)d_ws;
    float* out = (float*)d_out;

    k2_fused<<<B_ * N_ / 8, 256, 0, stream>>>(A, X, E, kn_w1, kn_b1,
                                              kn_w2, kn_b2, root_w, conv_b, ws);
    k3_head<<<B_, 256, 0, stream>>>(fc_w, fc_b, out_w, out_b, ws, out);
}

// Round 5
// 105.585 us; speedup vs baseline: 1.0214x; 1.0214x over previous
//
#include <hip/hip_runtime.h>
#include <math.h>

#define B_    16
#define N_    128
#define F_IN_ 8
#define S_    8
#define F_OUT_ 64
#define KN_HID_ 32
#define FC_HID_ 32

// workspace layout (float offsets)
//  nodes: [B*N][F_OUT] = 131072  (post-relu node features, pooled by k3)
#define NODE_OFF  0

// walk the 2x64-bit adjacency mask (wave-uniform); returns -1 when empty
__device__ __forceinline__ int next_edge(unsigned long long& lo,
                                         unsigned long long& hi) {
    if (lo) { int i = __builtin_ctzll(lo); lo &= lo - 1; return i; }
    if (hi) { int i = __builtin_ctzll(hi) + 64; hi &= hi - 1; return i; }
    return -1;
}

// ---------------------------------------------------------------------------
// k2: fused ECCConv via the T-factorization. ONE NODE PER WAVE (8 waves/CU).
//   T[k,f]  = sum_{i active} h[b,n,i,k] * X[b,i,f]   (32x8 per node)
//   T[32,f] = sum_{i active} X[b,i,f]                (bias row)
//   node[o] = relu( sum_{kf} T[kf]*w2ext[kf,o] + X[b,n]@root_w + conv_b )
// E rows read on demand per ACTIVE edge (32 B broadcast), prefetch depth 2.
// Grid: 512 blocks x 256 thr; block = 4 nodes (same batch), wave = 1 node.
// ---------------------------------------------------------------------------
__global__ __launch_bounds__(256) void k2_fused(
    const float* __restrict__ A, const float* __restrict__ X,
    const float* __restrict__ E,
    const float* __restrict__ kn_w1, const float* __restrict__ kn_b1,
    const float* __restrict__ kn_w2, const float* __restrict__ kn_b2,
    const float* __restrict__ root_w, const float* __restrict__ conv_b,
    float* __restrict__ ws)
{
    __shared__ float Xlds[N_ * F_IN_];          // 4 KB, whole X row of batch b
    __shared__ float Tlds[4][264];              // 4.2 KB (one T per wave)

    const int t    = threadIdx.x;
    const int lane = t & 63;
    const int wave = t >> 6;
    const int h2   = lane >> 5;                 // f-group: 0 -> f 0..3, 1 -> 4..7
    const int j    = lane & 31;                 // h index this lane owns
    const int b    = blockIdx.x >> 5;           // 32 blocks per batch
    const int bn   = blockIdx.x * 4 + wave;     // this wave's node

    // stage X[b,:,:] (4 KB) once per block
    ((float4*)Xlds)[t] = ((const float4*)(X + b * N_ * F_IN_))[t];

    // per-lane column j of kn_w1
    float w1j[S_];
#pragma unroll
    for (int s = 0; s < S_; ++s) w1j[s] = kn_w1[s * KN_HID_ + j];
    const float b1j = kn_b1[j];

    // adjacency row -> wave-uniform masks
    const float a0 = A[(size_t)bn * N_ + lane];
    const float a1 = A[(size_t)bn * N_ + 64 + lane];
    unsigned long long mlo = __ballot(a0 != 0.f);
    unsigned long long mhi = __ballot(a1 != 0.f);

    __syncthreads();   // Xlds cross-wave visibility

    const float4* __restrict__ Xl4 = (const float4*)Xlds;
    const float* __restrict__ Eb = E + (size_t)bn * N_ * S_ + (lane & 7);

    // ---- edge phase: software pipeline, 2 E-loads in flight ----------------
    float T[4]  = {0.f, 0.f, 0.f, 0.f};
    float xs[4] = {0.f, 0.f, 0.f, 0.f};

    int   i0 = next_edge(mlo, mhi);
    float e0 = (i0 >= 0) ? Eb[i0 * S_] : 0.f;
    int   i1 = (i0 >= 0) ? next_edge(mlo, mhi) : -1;
    float e1 = (i1 >= 0) ? Eb[i1 * S_] : 0.f;

    while (i0 >= 0) {
        // issue prefetch for edge i+2 before the compute chain
        const int   i2 = (i1 >= 0) ? next_edge(mlo, mhi) : -1;
        const float e2 = (i2 >= 0) ? Eb[i2 * S_] : 0.f;

        float hv = b1j;
#pragma unroll
        for (int s = 0; s < S_; ++s)
            hv += __shfl(e0, s) * w1j[s];
        hv = hv > 0.f ? hv : 0.f;               // h[j]

        const float4 xf = Xl4[i0 * 2 + h2];     // LDS broadcast
        T[0] += hv * xf.x;  T[1] += hv * xf.y;
        T[2] += hv * xf.z;  T[3] += hv * xf.w;
        xs[0] += xf.x; xs[1] += xf.y; xs[2] += xf.z; xs[3] += xf.w;

        i0 = i1; e0 = e1;
        i1 = i2; e1 = e2;
    }

    // T[k,f] -> LDS at kf = k*8+f; bias row kf = 256..263
    float4* __restrict__ Tl4 = (float4*)Tlds[wave];
    Tl4[j * 2 + h2] = make_float4(T[0], T[1], T[2], T[3]);
    if (j == 0)
        Tl4[64 + h2] = make_float4(xs[0], xs[1], xs[2], xs[3]);
    // same-wave LDS write->read: compiler inserts lgkmcnt waits, no barrier

    // ---- contraction: lane=(g,q); o in [4q,4q+4), kf = g,g+4,... -----------
    const int q = lane & 15;
    const int g = lane >> 4;
    const float* __restrict__ T0 = Tlds[wave];
    const float4* __restrict__ W4 = (const float4*)kn_w2;
    const float4* __restrict__ B4 = (const float4*)kn_b2;

    float4 acc = make_float4(0.f, 0.f, 0.f, 0.f);
#pragma unroll 8
    for (int kf = g; kf < 256; kf += 4) {
        const float4 w = W4[kf * 16 + q];       // coalesced 16B, L1-hot
        const float t0 = T0[kf];                // 4 addrs -> LDS broadcast
        acc.x += t0 * w.x; acc.y += t0 * w.y; acc.z += t0 * w.z; acc.w += t0 * w.w;
    }
#pragma unroll
    for (int f = g; f < F_IN_; f += 4) {
        const float4 w = B4[f * 16 + q];
        const float t0 = T0[256 + f];
        acc.x += t0 * w.x; acc.y += t0 * w.y; acc.z += t0 * w.z; acc.w += t0 * w.w;
    }

    // butterfly-reduce over g (lanes q, q+16, q+32, q+48)
#pragma unroll
    for (int d = 16; d < 64; d <<= 1) {
        acc.x += __shfl_xor(acc.x, d); acc.y += __shfl_xor(acc.y, d);
        acc.z += __shfl_xor(acc.z, d); acc.w += __shfl_xor(acc.w, d);
    }

    // ---- epilogue: + X[b,n]@root_w + conv_b, relu, store (g==0 lanes) ------
    const float4* __restrict__ R4 = (const float4*)root_w;
    const float4 cb = ((const float4*)conv_b)[q];
    const int n = bn & (N_ - 1);
    float4 r = acc;
    r.x += cb.x; r.y += cb.y; r.z += cb.z; r.w += cb.w;
#pragma unroll
    for (int f = 0; f < F_IN_; ++f) {
        const float xv = Xlds[n * F_IN_ + f];
        const float4 rw = R4[f * 16 + q];
        r.x += xv * rw.x; r.y += xv * rw.y; r.z += xv * rw.z; r.w += xv * rw.w;
    }
    r.x = r.x > 0.f ? r.x : 0.f;  r.y = r.y > 0.f ? r.y : 0.f;
    r.z = r.z > 0.f ? r.z : 0.f;  r.w = r.w > 0.f ? r.w : 0.f;
    if (g == 0)
        ((float4*)(ws + NODE_OFF + (size_t)bn * F_OUT_))[q] = r;
}

// ---------------------------------------------------------------------------
// k3: pooling + head. One 256-thread block per batch element.
// ---------------------------------------------------------------------------
__global__ __launch_bounds__(256) void k3_head(
    const float* __restrict__ fc_w, const float* __restrict__ fc_b,
    const float* __restrict__ out_w, const float* __restrict__ out_b,
    const float* __restrict__ ws, float* __restrict__ out)
{
    const int b = blockIdx.x;
    const int t = threadIdx.x;
    const int o = t & 63;
    const int g = t >> 6;

    float p = 0.f;
    for (int n = g; n < N_; n += 4)
        p += ws[NODE_OFF + (size_t)(b * N_ + n) * F_OUT_ + o];

    __shared__ float red[4][F_OUT_];
    __shared__ float pm[F_OUT_];
    __shared__ float y[FC_HID_];
    red[g][o] = p;
    __syncthreads();

    if (t < F_OUT_)
        pm[t] = (red[0][t] + red[1][t] + red[2][t] + red[3][t]) * (1.0f / (float)N_);
    __syncthreads();

    if (t < FC_HID_) {
        float v = fc_b[t];
#pragma unroll
        for (int o2 = 0; o2 < F_OUT_; ++o2) v += pm[o2] * fc_w[o2 * FC_HID_ + t];
        y[t] = v > 0.f ? v : 0.f;
    }
    __syncthreads();

    if (t == 0) {
        float z = out_b[0];
#pragma unroll
        for (int qq = 0; qq < FC_HID_; ++qq) z += y[qq] * out_w[qq];
        out[b] = 1.f / (1.f + expf(-z));
    }
}

extern "C" void kernel_launch(void* const* d_in, const int* in_sizes, int n_in,
                              void* d_out, int out_size, void* d_ws, size_t ws_size,
                              hipStream_t stream)
{
    const float* A      = (const float*)d_in[0];
    const float* X      = (const float*)d_in[1];
    const float* E      = (const float*)d_in[2];
    const float* kn_w1  = (const float*)d_in[3];
    const float* kn_b1  = (const float*)d_in[4];
    const float* kn_w2  = (const float*)d_in[5];
    const float* kn_b2  = (const float*)d_in[6];
    const float* root_w = (const float*)d_in[7];
    const float* conv_b = (const float*)d_in[8];
    const float* fc_w   = (const float*)d_in[9];
    const float* fc_b   = (const float*)d_in[10];
    const float* out_w  = (const float*)d_in[11];
    const float* out_b  = (const float*)d_in[12];

    float* ws  = (float*)d_ws;
    float* out = (float*)d_out;

    k2_fused<<<B_ * N_ / 4, 256, 0, stream>>>(A, X, E, kn_w1, kn_b1,
                                              kn_w2, kn_b2, root_w, conv_b, ws);
    k3_head<<<B_, 256, 0, stream>>>(fc_w, fc_b, out_w, out_b, ws, out);
}